// Round 7
// baseline (1140.540 us; speedup 1.0000x reference)
//
#include <hip/hip_runtime.h>
#include <hip/hip_bf16.h>
#include <math.h>

#define Bsz 4
#define Ssz 2048
#define Dsz 768
#define Hn  12
#define DHn 64
#define DFn 3072
#define NTOK (Bsz*Ssz)          // 8192 rows
#define EPSL 1e-5f

typedef __attribute__((ext_vector_type(8))) short bf16x8;
typedef __attribute__((ext_vector_type(4))) float f32x4;

__device__ __forceinline__ unsigned short f2bf(float f) {
    unsigned int u = __float_as_uint(f);
    u += 0x7fffu + ((u >> 16) & 1u);
    return (unsigned short)(u >> 16);
}
__device__ __forceinline__ float bf2f(unsigned short h) {
    return __uint_as_float(((unsigned int)h) << 16);
}

// XCD swizzle: all n-blocks of an m-tile share bid&7 -> same XCD L2 (A reuse).
__device__ __forceinline__ void swizzle_mn(int bid, int mtot, int nb, int& m, int& n)
{
    const int xcd = bid & 7;
    const int idx = bid >> 3;
    m = xcd * (mtot >> 3) + idx / nb;
    n = idx % nb;
}

// ---------------------------------------------------------------------------
// Weight transpose+split: W[K,N] fp32 -> Wh,Wl [N,K] bf16 (B^T layout).
// ---------------------------------------------------------------------------
__global__ __launch_bounds__(256)
void wsplit_k(const float* __restrict__ W, unsigned short* __restrict__ Wh,
              unsigned short* __restrict__ Wl, int K, int N)
{
    __shared__ float tile[32][33];
    const int n0 = blockIdx.x * 32, k0 = blockIdx.y * 32;
    const int x = threadIdx.x, y = threadIdx.y;
    #pragma unroll
    for (int i = 0; i < 4; i++)
        tile[y + 8 * i][x] = W[(size_t)(k0 + y + 8 * i) * N + n0 + x];
    __syncthreads();
    #pragma unroll
    for (int i = 0; i < 4; i++) {
        float v = tile[x][y + 8 * i];
        unsigned short hb = f2bf(v);
        size_t o = (size_t)(n0 + y + 8 * i) * K + k0 + x;
        Wh[o] = hb;
        Wl[o] = f2bf(v - bf2f(hb));
    }
}

// ---------------------------------------------------------------------------
// Input presplit: fp32 [NTOK,Dsz] -> bf16 hi(+lo) row-major.
// seg 0=Q(hi+lo) 1=K(hi+lo) 2=V(hi only).
// ---------------------------------------------------------------------------
__global__ __launch_bounds__(256)
void presplit_k(const float* __restrict__ Qf, const float* __restrict__ Kf,
                const float* __restrict__ Vf,
                unsigned short* __restrict__ Qh, unsigned short* __restrict__ Ql,
                unsigned short* __restrict__ Kh, unsigned short* __restrict__ Kl,
                unsigned short* __restrict__ Vh)
{
    const int blocksPerSeg = (NTOK * Dsz) / 2048;        // 3072
    const int seg = blockIdx.x / blocksPerSeg;
    const int idx = ((blockIdx.x % blocksPerSeg) * 256 + threadIdx.x) * 8;
    const float* src = (seg == 0) ? Qf : (seg == 1) ? Kf : Vf;

    float4 a = *(const float4*)(src + idx);
    float4 b = *(const float4*)(src + idx + 4);
    float fv[8] = {a.x, a.y, a.z, a.w, b.x, b.y, b.z, b.w};

    bf16x8 h8, l8;
    #pragma unroll
    for (int e = 0; e < 8; e++) {
        unsigned short hb = f2bf(fv[e]);
        h8[e] = (short)hb;
        l8[e] = (short)f2bf(fv[e] - bf2f(hb));
    }
    unsigned short* Hp = (seg == 0) ? Qh : (seg == 1) ? Kh : Vh;
    *(bf16x8*)(Hp + idx) = h8;
    if (seg < 2) {
        unsigned short* Lp = (seg == 0) ? Ql : Kl;
        *(bf16x8*)(Lp + idx) = l8;
    }
}

// ---------------------------------------------------------------------------
// Fused QKV projection, XCD-swizzled.  A and B both pre-split bf16, staged
// purely via global_load_lds (no VALU conversion in the K-loop).
// Q outputs are pre-scaled by 0.125 (exact power-of-2: commutes with the
// bf16 split and with the QK^T dot product) so attn skips the score scale.
// ---------------------------------------------------------------------------
__global__ __launch_bounds__(256)
void qkv_mfma(const unsigned short* __restrict__ Qsh, const unsigned short* __restrict__ Qsl,
              const unsigned short* __restrict__ Ksh, const unsigned short* __restrict__ Ksl,
              const unsigned short* __restrict__ Vsh,
              const unsigned short* __restrict__ Wqh, const unsigned short* __restrict__ Wql,
              const unsigned short* __restrict__ Wkh, const unsigned short* __restrict__ Wkl,
              const unsigned short* __restrict__ Wvh, const unsigned short* __restrict__ Wvl,
              const float* __restrict__ bq, const float* __restrict__ bk,
              const float* __restrict__ bv,
              unsigned short* __restrict__ qh, unsigned short* __restrict__ ql,
              unsigned short* __restrict__ kh, unsigned short* __restrict__ kl,
              unsigned short* __restrict__ vout)
{
    __shared__ short smem[16384];
    short* As_h = smem;
    short* As_l = smem + 4096;
    short* Bs_h = smem + 8192;
    short* Bs_l = smem + 12288;

    const int t    = threadIdx.x;
    const int lane = t & 63;
    const int w    = t >> 6;
    const int wm   = w >> 1;
    const int wn   = w & 1;

    int m_tile, nblk;
    swizzle_mn(blockIdx.x, 192, 6, m_tile, nblk);
    const int which = m_tile / 64;               // 0=Q 1=K 2=V
    const int m0    = (m_tile % 64) * 128;
    const int n0    = nblk * 128;

    const unsigned short* Ah = (which == 0) ? Qsh : (which == 1) ? Ksh : Vsh;
    const unsigned short* Al = (which == 0) ? Qsl : Ksl;   // unused for V
    const unsigned short* Bh = (which == 0) ? Wqh : (which == 1) ? Wkh : Wvh;
    const unsigned short* Bl = (which == 0) ? Wql : (which == 1) ? Wkl : Wvl;
    const float* bias = (which == 0) ? bq : (which == 1) ? bk : bv;

    f32x4 acc[4][4];
    #pragma unroll
    for (int i = 0; i < 4; i++)
        #pragma unroll
        for (int j = 0; j < 4; j++)
            acc[i][j] = (f32x4){0.f, 0.f, 0.f, 0.f};

    const int fr = lane & 15;
    const int q8 = (lane >> 4) * 8;

    for (int k0 = 0; k0 < Dsz; k0 += 32) {
        __syncthreads();
        #pragma unroll
        for (int it = 0; it < 2; it++) {
            const int p   = t + 256 * it;
            const int row = p >> 2;
            const int c8  = (p & 3) * 8;
            const unsigned short* ga_h = Ah + (size_t)(m0 + row) * Dsz + k0 + c8;
            const unsigned short* gb_h = Bh + (size_t)(n0 + row) * Dsz + k0 + c8;
            __builtin_amdgcn_global_load_lds((const __attribute__((address_space(1))) void*)ga_h,
                (__attribute__((address_space(3))) void*)(As_h + p * 8), 16, 0, 0);
            __builtin_amdgcn_global_load_lds((const __attribute__((address_space(1))) void*)gb_h,
                (__attribute__((address_space(3))) void*)(Bs_h + p * 8), 16, 0, 0);
            if (which < 2) {
                const unsigned short* ga_l = Al + (size_t)(m0 + row) * Dsz + k0 + c8;
                const unsigned short* gb_l = Bl + (size_t)(n0 + row) * Dsz + k0 + c8;
                __builtin_amdgcn_global_load_lds((const __attribute__((address_space(1))) void*)ga_l,
                    (__attribute__((address_space(3))) void*)(As_l + p * 8), 16, 0, 0);
                __builtin_amdgcn_global_load_lds((const __attribute__((address_space(1))) void*)gb_l,
                    (__attribute__((address_space(3))) void*)(Bs_l + p * 8), 16, 0, 0);
            }
        }
        __syncthreads();

        bf16x8 a_h[4], a_l[4], b_h[4], b_l[4];
        #pragma unroll
        for (int i = 0; i < 4; i++) {
            const int ra = (wm * 64 + i * 16 + fr) * 32 + q8;
            const int rb = (wn * 64 + i * 16 + fr) * 32 + q8;
            a_h[i] = *(const bf16x8*)&As_h[ra];
            b_h[i] = *(const bf16x8*)&Bs_h[rb];
            if (which < 2) {
                a_l[i] = *(const bf16x8*)&As_l[ra];
                b_l[i] = *(const bf16x8*)&Bs_l[rb];
            }
        }
        if (which < 2) {
            #pragma unroll
            for (int i = 0; i < 4; i++)
                #pragma unroll
                for (int j = 0; j < 4; j++) {
                    acc[i][j] = __builtin_amdgcn_mfma_f32_16x16x32_bf16(a_l[i], b_h[j], acc[i][j], 0, 0, 0);
                    acc[i][j] = __builtin_amdgcn_mfma_f32_16x16x32_bf16(a_h[i], b_l[j], acc[i][j], 0, 0, 0);
                    acc[i][j] = __builtin_amdgcn_mfma_f32_16x16x32_bf16(a_h[i], b_h[j], acc[i][j], 0, 0, 0);
                }
        } else {
            #pragma unroll
            for (int i = 0; i < 4; i++)
                #pragma unroll
                for (int j = 0; j < 4; j++)
                    acc[i][j] = __builtin_amdgcn_mfma_f32_16x16x32_bf16(a_h[i], b_h[j], acc[i][j], 0, 0, 0);
        }
    }

    const int quad = lane >> 4;
    #pragma unroll
    for (int i = 0; i < 4; i++)
        #pragma unroll
        for (int j = 0; j < 4; j++) {
            const int n  = n0 + wn * 64 + j * 16 + fr;
            const float bn = bias[n];
            const int hh = n >> 6, dh = n & 63;
            #pragma unroll
            for (int r = 0; r < 4; r++) {
                const int m = m0 + wm * 64 + i * 16 + quad * 4 + r;
                const int bb = m >> 11, s = m & 2047;
                const size_t o = (((size_t)bb * Hn + hh) * Ssz + s) * DHn + dh;
                float v = acc[i][j][r] + bn;
                if (which == 0) {
                    v *= 0.125f;             // fold softmax scale (exact)
                    unsigned short hb = f2bf(v);
                    qh[o] = hb; ql[o] = f2bf(v - bf2f(hb));
                } else if (which == 1) {
                    unsigned short hb = f2bf(v);
                    kh[o] = hb; kl[o] = f2bf(v - bf2f(hb));
                } else {
                    vout[o] = f2bf(v);
                }
            }
        }
}

// ---------------------------------------------------------------------------
// Per-head transpose: [B,H,S,DH] bf16 -> [B,H,DH,S] bf16.
// ---------------------------------------------------------------------------
__global__ __launch_bounds__(256)
void vtrans_k(const unsigned short* __restrict__ src, unsigned short* __restrict__ dst)
{
    __shared__ unsigned short tl[32][33];
    const int s0 = blockIdx.x * 32;
    const int d0 = blockIdx.y * 32;
    const int hd = blockIdx.z;
    const int x = threadIdx.x, y = threadIdx.y;
    const size_t base = (size_t)hd * Ssz * DHn;
    #pragma unroll
    for (int i = 0; i < 4; i++)
        tl[y + 8 * i][x] = src[base + (size_t)(s0 + y + 8 * i) * DHn + d0 + x];
    __syncthreads();
    #pragma unroll
    for (int i = 0; i < 4; i++)
        dst[base + (size_t)(d0 + y + 8 * i) * Ssz + s0 + x] = tl[x][y + 8 * i];
}

// ---------------------------------------------------------------------------
// Generic MFMA GEMM, XCD-swizzled (1-D grid). A [M,K] bf16 (+opt lo);
// B [N,K] bf16 (+opt lo).  BM = 128 (4 waves of 64x64) or 64 (4 waves of
// 32x64) -- BM=64 gives grid 2x for skinny-N GEMMs (even CU residency).
// MODE 1: +bias +res, fp32 out.  MODE 2: GELU -> bf16 out.  MODE 3: fp32 out.
// ---------------------------------------------------------------------------
template<int MODE, bool ASPLIT, bool BSPLIT, int BM>
__global__ __launch_bounds__(256)
void gemm_mfma(const unsigned short* __restrict__ Ah, const unsigned short* __restrict__ Al,
               const unsigned short* __restrict__ Bh, const unsigned short* __restrict__ Bl,
               const float* __restrict__ bias, const float* __restrict__ res,
               float* __restrict__ Cf, unsigned short* __restrict__ Cb,
               int M, int N, int K)
{
    constexpr int MI = BM / 32;               // acc rows of 16 per wave
    __shared__ short smem[16384];
    short* As_h = smem;
    short* As_l = smem + 4096;
    short* Bs_h = smem + 8192;
    short* Bs_l = smem + 12288;

    const int t    = threadIdx.x;
    const int lane = t & 63;
    const int w    = t >> 6;
    const int wm   = w >> 1;
    const int wn   = w & 1;

    int mt, nt_;
    swizzle_mn(blockIdx.x, M / BM, N >> 7, mt, nt_);
    const int m0 = mt * BM;
    const int n0 = nt_ * 128;

    f32x4 acc[MI][4];
    #pragma unroll
    for (int i = 0; i < MI; i++)
        #pragma unroll
        for (int j = 0; j < 4; j++)
            acc[i][j] = (f32x4){0.f, 0.f, 0.f, 0.f};

    const int fr = lane & 15;
    const int q8 = (lane >> 4) * 8;

    for (int k0 = 0; k0 < K; k0 += 32) {
        __syncthreads();
        // ---- stage A (BM rows) ----
        #pragma unroll
        for (int it = 0; it < BM / 64; it++) {
            const int p   = t + 256 * it;
            const int row = p >> 2;
            const int c8  = (p & 3) * 8;
            const unsigned short* ga_h = Ah + (size_t)(m0 + row) * K + k0 + c8;
            __builtin_amdgcn_global_load_lds((const __attribute__((address_space(1))) void*)ga_h,
                (__attribute__((address_space(3))) void*)(As_h + p * 8), 16, 0, 0);
            if (ASPLIT) {
                const unsigned short* ga_l = Al + (size_t)(m0 + row) * K + k0 + c8;
                __builtin_amdgcn_global_load_lds((const __attribute__((address_space(1))) void*)ga_l,
                    (__attribute__((address_space(3))) void*)(As_l + p * 8), 16, 0, 0);
            }
        }
        // ---- stage B (128 rows) ----
        #pragma unroll
        for (int it = 0; it < 2; it++) {
            const int p   = t + 256 * it;
            const int row = p >> 2;
            const int c8  = (p & 3) * 8;
            const unsigned short* gb_h = Bh + (size_t)(n0 + row) * K + k0 + c8;
            __builtin_amdgcn_global_load_lds((const __attribute__((address_space(1))) void*)gb_h,
                (__attribute__((address_space(3))) void*)(Bs_h + p * 8), 16, 0, 0);
            if (BSPLIT) {
                const unsigned short* gb_l = Bl + (size_t)(n0 + row) * K + k0 + c8;
                __builtin_amdgcn_global_load_lds((const __attribute__((address_space(1))) void*)gb_l,
                    (__attribute__((address_space(3))) void*)(Bs_l + p * 8), 16, 0, 0);
            }
        }
        __syncthreads();

        bf16x8 a_h[MI], a_l[MI], b_h[4], b_l[4];
        #pragma unroll
        for (int i = 0; i < MI; i++) {
            const int ra = (wm * (BM / 2) + i * 16 + fr) * 32 + q8;
            a_h[i] = *(const bf16x8*)&As_h[ra];
            if (ASPLIT) a_l[i] = *(const bf16x8*)&As_l[ra];
        }
        #pragma unroll
        for (int j = 0; j < 4; j++) {
            const int rb = (wn * 64 + j * 16 + fr) * 32 + q8;
            b_h[j] = *(const bf16x8*)&Bs_h[rb];
            if (BSPLIT) b_l[j] = *(const bf16x8*)&Bs_l[rb];
        }
        #pragma unroll
        for (int i = 0; i < MI; i++)
            #pragma unroll
            for (int j = 0; j < 4; j++) {
                if (ASPLIT)
                    acc[i][j] = __builtin_amdgcn_mfma_f32_16x16x32_bf16(a_l[i], b_h[j], acc[i][j], 0, 0, 0);
                if (BSPLIT)
                    acc[i][j] = __builtin_amdgcn_mfma_f32_16x16x32_bf16(a_h[i], b_l[j], acc[i][j], 0, 0, 0);
                acc[i][j] = __builtin_amdgcn_mfma_f32_16x16x32_bf16(a_h[i], b_h[j], acc[i][j], 0, 0, 0);
            }
    }

    const int quad = lane >> 4;
    #pragma unroll
    for (int i = 0; i < MI; i++)
        #pragma unroll
        for (int j = 0; j < 4; j++) {
            const int n  = n0 + wn * 64 + j * 16 + fr;
            const float bn = bias[n];
            #pragma unroll
            for (int r = 0; r < 4; r++) {
                const int m = m0 + wm * (BM / 2) + i * 16 + quad * 4 + r;
                float v = acc[i][j][r] + bn;
                if (MODE == 1) {
                    v += res[(size_t)m * N + n];
                    Cf[(size_t)m * N + n] = v;
                } else if (MODE == 2) {
                    v = 0.5f * v * (1.0f + erff(v * 0.70710678118654752f));
                    Cb[(size_t)m * N + n] = f2bf(v);
                } else {
                    Cf[(size_t)m * N + n] = v;
                }
            }
        }
}

// ---------------------------------------------------------------------------
// MFMA flash attention, barrier-free streaming variant.
// K/V/Q working set is L1/L2-resident (24 KB/kt-step, shared by all 4 waves
// and by same-head blocks) -> NO LDS staging, NO __syncthreads.  Every MFMA
// operand fragment is a contiguous 16B bf16x8 in global memory
// (row*stride + (kc*4+quad)*8), loaded directly global->VGPR per use
// (m169 pattern: de-stage cache-fit read-only operands).
// LDS holds only the per-wave P buffer (16 KB/block); grid (32 q-tiles,
// 48 heads) = 1536 blocks, fully co-resident at 6 blocks/CU.
// Shift-free softmax; Q arrives pre-scaled by 1/8.
// ---------------------------------------------------------------------------
__global__ __launch_bounds__(256)
void attn_mfma(const unsigned short* __restrict__ qh, const unsigned short* __restrict__ ql,
               const unsigned short* __restrict__ kh, const unsigned short* __restrict__ kl,
               const unsigned short* __restrict__ vt, unsigned short* __restrict__ ch)
{
    const int q0  = blockIdx.x * 64;
    const int hid = blockIdx.y;
    const int b   = hid / Hn;
    const int h   = hid - b * Hn;
    const int t    = threadIdx.x;
    const int lane = t & 63;
    const int w    = t >> 6;
    const int fr   = lane & 15;
    const int quad = lane >> 4;

    __shared__ float Pws[4096];              // 4 waves x 1024 f32 = 16 KB
    float* Pw = Pws + w * 1024;

    const size_t hoff = (size_t)hid * Ssz * DHn;
    const unsigned short* Kh_g = kh + hoff;
    const unsigned short* Kl_g = kl + hoff;
    const unsigned short* Vt_g = vt + hoff;

    // Q fragments straight from global (row q0 + w*16 + fr).
    bf16x8 qfh[2], qfl[2];
    {
        const unsigned short* qp  = qh + hoff + (size_t)(q0 + w * 16 + fr) * DHn;
        const unsigned short* qlp = ql + hoff + (size_t)(q0 + w * 16 + fr) * DHn;
        #pragma unroll
        for (int kc = 0; kc < 2; kc++) {
            qfh[kc] = *(const bf16x8*)(qp  + (kc * 4 + quad) * 8);
            qfl[kc] = *(const bf16x8*)(qlp + (kc * 4 + quad) * 8);
        }
    }

    f32x4 O[4];
    #pragma unroll
    for (int d = 0; d < 4; d++) O[d] = (f32x4){0.f, 0.f, 0.f, 0.f};
    float lp[4] = {0.f, 0.f, 0.f, 0.f};

    for (int kt = 0; kt < Ssz / 64; kt++) {
        const int kr = kt * 64;

        // ---- QK^T: K fragments direct from global ----
        f32x4 sc[4];
        #pragma unroll
        for (int nt = 0; nt < 4; nt++) sc[nt] = (f32x4){0.f, 0.f, 0.f, 0.f};
        __builtin_amdgcn_s_setprio(1);
        #pragma unroll
        for (int nt = 0; nt < 4; nt++) {
            const unsigned short* krh = Kh_g + (size_t)(kr + nt * 16 + fr) * DHn;
            const unsigned short* krl = Kl_g + (size_t)(kr + nt * 16 + fr) * DHn;
            #pragma unroll
            for (int kc = 0; kc < 2; kc++) {
                bf16x8 bh = *(const bf16x8*)(krh + (kc * 4 + quad) * 8);
                bf16x8 bl = *(const bf16x8*)(krl + (kc * 4 + quad) * 8);
                sc[nt] = __builtin_amdgcn_mfma_f32_16x16x32_bf16(qfl[kc], bh, sc[nt], 0, 0, 0);
                sc[nt] = __builtin_amdgcn_mfma_f32_16x16x32_bf16(qfh[kc], bl, sc[nt], 0, 0, 0);
                sc[nt] = __builtin_amdgcn_mfma_f32_16x16x32_bf16(qfh[kc], bh, sc[nt], 0, 0, 0);
            }
        }
        __builtin_amdgcn_s_setprio(0);

        // ---- softmax (shift-free), P staged via per-wave LDS (no barrier:
        //      wave-local buffer, DS ops in-order per wave) ----
        #pragma unroll
        for (int r = 0; r < 4; r++) {
            const int m = quad * 4 + r;
            #pragma unroll
            for (int nt = 0; nt < 4; nt++) {
                float p = __expf(sc[nt][r]);          // scale pre-folded into Q
                const int j  = nt * 16 + fr;
                const int c4 = j >> 2;
                Pw[(m * 16 + (c4 ^ m)) * 4 + (j & 3)] = p;
                lp[r] += p;
            }
        }

        // ---- PV: V fragments direct from global ----
        #pragma unroll
        for (int kc = 0; kc < 2; kc++) {
            const int c4a = kc * 8 + quad * 2;
            float4 pa = *(float4*)&Pw[(fr * 16 + (c4a ^ fr)) * 4];
            float4 pb = *(float4*)&Pw[(fr * 16 + ((c4a + 1) ^ fr)) * 4];
            union { bf16x8 v; __hip_bfloat162 b2[4]; } P;
            P.b2[0] = __float22bfloat162_rn(make_float2(pa.x, pa.y));
            P.b2[1] = __float22bfloat162_rn(make_float2(pa.z, pa.w));
            P.b2[2] = __float22bfloat162_rn(make_float2(pb.x, pb.y));
            P.b2[3] = __float22bfloat162_rn(make_float2(pb.z, pb.w));
            __builtin_amdgcn_s_setprio(1);
            #pragma unroll
            for (int dt = 0; dt < 4; dt++) {
                bf16x8 vh = *(const bf16x8*)(Vt_g + (size_t)(dt * 16 + fr) * Ssz
                                             + kr + (kc * 4 + quad) * 8);
                O[dt] = __builtin_amdgcn_mfma_f32_16x16x32_bf16(P.v, vh, O[dt], 0, 0, 0);
            }
            __builtin_amdgcn_s_setprio(0);
        }
    }

    #pragma unroll
    for (int r = 0; r < 4; r++) {
        float ls = lp[r];
        #pragma unroll
        for (int msk = 1; msk < 16; msk <<= 1) ls += __shfl_xor(ls, msk);
        const float linv = 1.0f / ls;
        const int s = q0 + w * 16 + quad * 4 + r;
        unsigned short* och = ch + ((size_t)b * Ssz + s) * Dsz + h * DHn;
        #pragma unroll
        for (int dt = 0; dt < 4; dt++)
            och[dt * 16 + fr] = f2bf(O[dt][r] * linv);
    }
}

// ---------------------------------------------------------------------------
// LayerNorm over D=768; writes single bf16 (FFN1 is 2-term: A-hi only).
// ---------------------------------------------------------------------------
__global__ __launch_bounds__(256)
void ln_k(const float* __restrict__ x, const float* __restrict__ g,
          const float* __restrict__ bb, unsigned short* __restrict__ yh)
{
    const int row = blockIdx.x;
    const float* xr = x + (size_t)row * Dsz;
    unsigned short* yhr = yh + (size_t)row * Dsz;
    const int t = threadIdx.x;

    float v0 = xr[t], v1 = xr[t + 256], v2 = xr[t + 512];
    float s = v0 + v1 + v2;
    #pragma unroll
    for (int o = 1; o < 64; o <<= 1) s += __shfl_xor(s, o, 64);

    __shared__ float red1[4];
    __shared__ float red2[4];
    const int wid = t >> 6, lane = t & 63;
    if (lane == 0) red1[wid] = s;
    __syncthreads();
    const float mean = (red1[0] + red1[1] + red1[2] + red1[3]) * (1.0f / Dsz);

    float d0 = v0 - mean, d1 = v1 - mean, d2 = v2 - mean;
    float vs = d0 * d0 + d1 * d1 + d2 * d2;
    #pragma unroll
    for (int o = 1; o < 64; o <<= 1) vs += __shfl_xor(vs, o, 64);
    if (lane == 0) red2[wid] = vs;
    __syncthreads();
    const float var = (red2[0] + red2[1] + red2[2] + red2[3]) * (1.0f / Dsz);
    const float inv = rsqrtf(var + EPSL);

    yhr[t]       = f2bf(d0 * inv * g[t]       + bb[t]);
    yhr[t + 256] = f2bf(d1 * inv * g[t + 256] + bb[t + 256]);
    yhr[t + 512] = f2bf(d2 * inv * g[t + 512] + bb[t + 512]);
}

// ---------------------------------------------------------------------------
extern "C" void kernel_launch(void* const* d_in, const int* in_sizes, int n_in,
                              void* d_out, int out_size, void* d_ws, size_t ws_size,
                              hipStream_t stream)
{
    (void)in_sizes; (void)n_in; (void)out_size; (void)ws_size;
    const float* Q    = (const float*)d_in[0];
    const float* Kin  = (const float*)d_in[1];
    const float* Vin  = (const float*)d_in[2];
    const float* Wq   = (const float*)d_in[3];
    const float* bq   = (const float*)d_in[4];
    const float* Wk   = (const float*)d_in[5];
    const float* bk   = (const float*)d_in[6];
    const float* Wv   = (const float*)d_in[7];
    const float* bv   = (const float*)d_in[8];
    const float* Wo   = (const float*)d_in[9];
    const float* bo   = (const float*)d_in[10];
    const float* ln_g = (const float*)d_in[11];
    const float* ln_b = (const float*)d_in[12];
    const float* W1   = (const float*)d_in[13];
    const float* b1   = (const float*)d_in[14];
    const float* W2   = (const float*)d_in[15];
    const float* b2   = (const float*)d_in[16];
    float* out = (float*)d_out;

    const size_t NT = (size_t)NTOK * Dsz;              // 6291456 elems
    unsigned short* usws = (unsigned short*)d_ws;
    unsigned short* qh  = usws + 0 * NT;
    unsigned short* ql  = usws + 1 * NT;
    unsigned short* kh  = usws + 2 * NT;               // later LN-out hh
    unsigned short* kl  = usws + 3 * NT;
    unsigned short* vt  = usws + 4 * NT;
    unsigned short* ch  = usws + 6 * NT;               // V pre-T; later ctx bf16
    unsigned short* wsp = usws + 8 * NT;
    const size_t SW = (size_t)Dsz * Dsz;
    unsigned short* Wqh = wsp + 0 * SW;
    unsigned short* Wql = wsp + 1 * SW;
    unsigned short* Wkh = wsp + 2 * SW;
    unsigned short* Wkl = wsp + 3 * SW;
    unsigned short* Wvh = wsp + 4 * SW;
    unsigned short* Wvl = wsp + 5 * SW;
    unsigned short* Woh = wsp + 6 * SW;
    unsigned short* Wol = wsp + 7 * SW;
    unsigned short* W1h = wsp + 8 * SW;
    unsigned short* W1l = wsp + 12 * SW;
    unsigned short* W2h = wsp + 16 * SW;
    unsigned short* W2l = wsp + 20 * SW;
    float*          hpre = (float*)usws;               // fp32 over qh+ql
    unsigned short* hh   = kh;
    unsigned short* hbuf = usws + 4 * NT;              // FFN hidden bf16 [8192,3072]

    // presplit scratch: regions free until vtrans/FFN2.
    unsigned short* Qsh = usws + 4 * NT;
    unsigned short* Qsl = usws + 5 * NT;
    unsigned short* Ksh = usws + 7 * NT;
    unsigned short* Ksl = (unsigned short*)d_out;
    unsigned short* Vsh = (unsigned short*)d_out + NT;

    dim3 wb(32, 8);
    wsplit_k<<<dim3(Dsz / 32, Dsz / 32), wb, 0, stream>>>(Wq, Wqh, Wql, Dsz, Dsz);
    wsplit_k<<<dim3(Dsz / 32, Dsz / 32), wb, 0, stream>>>(Wk, Wkh, Wkl, Dsz, Dsz);
    wsplit_k<<<dim3(Dsz / 32, Dsz / 32), wb, 0, stream>>>(Wv, Wvh, Wvl, Dsz, Dsz);
    wsplit_k<<<dim3(Dsz / 32, Dsz / 32), wb, 0, stream>>>(Wo, Woh, Wol, Dsz, Dsz);
    wsplit_k<<<dim3(DFn / 32, Dsz / 32), wb, 0, stream>>>(W1, W1h, W1l, Dsz, DFn);
    wsplit_k<<<dim3(Dsz / 32, DFn / 32), wb, 0, stream>>>(W2, W2h, W2l, DFn, Dsz);

    // input presplit: Q,K -> hi+lo; V -> hi.
    presplit_k<<<3 * (NTOK * Dsz / 2048), 256, 0, stream>>>(
        Q, Kin, Vin, Qsh, Qsl, Ksh, Ksl, Vsh);

    // fused QKV projections, swizzled (V -> single bf16 into ch)
    qkv_mfma<<<1152, 256, 0, stream>>>(
        Qsh, Qsl, Ksh, Ksl, Vsh,
        Wqh, Wql, Wkh, Wkl, Wvh, Wvl, bq, bk, bv,
        qh, ql, kh, kl, ch);

    // V transpose -> vt [B,H,DH,S]
    vtrans_k<<<dim3(Ssz / 32, DHn / 32, Bsz * Hn), wb, 0, stream>>>(ch, vt);

    // flash attention -> ctx bf16 (ch); barrier-free, direct-global operands.
    // grid (q-tiles fastest) so same-head blocks co-schedule per XCD.
    attn_mfma<<<dim3(Ssz / 64, Bsz * Hn), 256, 0, stream>>>(qh, ql, kh, kl, vt, ch);

    // O projection (2-term) + bias + residual(Q) -> hpre fp32.  BM=64: grid
    // 768 = 3 blocks/CU even.
    gemm_mfma<1, false, true, 64><<<768, 256, 0, stream>>>(
        ch, nullptr, Woh, Wol, bo, Q, hpre, nullptr, NTOK, Dsz, Dsz);

    // LayerNorm -> single bf16 over kh
    ln_k<<<NTOK, 256, 0, stream>>>(hpre, ln_g, ln_b, hh);

    // FFN: FFN1 2-term (GELU -> bf16 hidden) BM=128 grid 1536;
    //      FFN2 1-term (fp32 out) BM=64 grid 768 (even residency).
    gemm_mfma<2, false, true, 128><<<1536, 256, 0, stream>>>(
        hh, nullptr, W1h, W1l, b1, nullptr, nullptr, hbuf, NTOK, DFn, Dsz);
    gemm_mfma<3, false, false, 64><<<768, 256, 0, stream>>>(
        hbuf, nullptr, W2h, nullptr, b2, nullptr, out, nullptr, NTOK, Dsz, DFn);
}

// Round 8
// 602.395 us; speedup vs baseline: 1.8933x; 1.8933x over previous
//
#include <hip/hip_runtime.h>
#include <hip/hip_bf16.h>
#include <math.h>

#define Bsz 4
#define Ssz 2048
#define Dsz 768
#define Hn  12
#define DHn 64
#define DFn 3072
#define NTOK (Bsz*Ssz)          // 8192 rows
#define EPSL 1e-5f

typedef __attribute__((ext_vector_type(8))) short bf16x8;
typedef __attribute__((ext_vector_type(4))) float f32x4;

__device__ __forceinline__ unsigned short f2bf(float f) {
    unsigned int u = __float_as_uint(f);
    u += 0x7fffu + ((u >> 16) & 1u);
    return (unsigned short)(u >> 16);
}
__device__ __forceinline__ float bf2f(unsigned short h) {
    return __uint_as_float(((unsigned int)h) << 16);
}

#define GLDS(gp, lp) __builtin_amdgcn_global_load_lds( \
    (const __attribute__((address_space(1))) void*)(gp), \
    (__attribute__((address_space(3))) void*)(lp), 16, 0, 0)

// XCD swizzle: all n-blocks of an m-tile share bid&7 -> same XCD L2 (A reuse).
__device__ __forceinline__ void swizzle_mn(int bid, int mtot, int nb, int& m, int& n)
{
    const int xcd = bid & 7;
    const int idx = bid >> 3;
    m = xcd * (mtot >> 3) + idx / nb;
    n = idx % nb;
}

// ---------------------------------------------------------------------------
// Weight transpose+split: W[K,N] fp32 -> Wh,Wl [N,K] bf16 (B^T layout).
// ---------------------------------------------------------------------------
__global__ __launch_bounds__(256)
void wsplit_k(const float* __restrict__ W, unsigned short* __restrict__ Wh,
              unsigned short* __restrict__ Wl, int K, int N)
{
    __shared__ float tile[32][33];
    const int n0 = blockIdx.x * 32, k0 = blockIdx.y * 32;
    const int x = threadIdx.x, y = threadIdx.y;
    #pragma unroll
    for (int i = 0; i < 4; i++)
        tile[y + 8 * i][x] = W[(size_t)(k0 + y + 8 * i) * N + n0 + x];
    __syncthreads();
    #pragma unroll
    for (int i = 0; i < 4; i++) {
        float v = tile[x][y + 8 * i];
        unsigned short hb = f2bf(v);
        size_t o = (size_t)(n0 + y + 8 * i) * K + k0 + x;
        Wh[o] = hb;
        Wl[o] = f2bf(v - bf2f(hb));
    }
}

// ---------------------------------------------------------------------------
// Input presplit: fp32 [NTOK,Dsz] -> bf16 hi(+lo) row-major.
// seg 0=Q(hi+lo) 1=K(hi+lo) 2=V(hi only).
// ---------------------------------------------------------------------------
__global__ __launch_bounds__(256)
void presplit_k(const float* __restrict__ Qf, const float* __restrict__ Kf,
                const float* __restrict__ Vf,
                unsigned short* __restrict__ Qh, unsigned short* __restrict__ Ql,
                unsigned short* __restrict__ Kh, unsigned short* __restrict__ Kl,
                unsigned short* __restrict__ Vh)
{
    const int blocksPerSeg = (NTOK * Dsz) / 2048;        // 3072
    const int seg = blockIdx.x / blocksPerSeg;
    const int idx = ((blockIdx.x % blocksPerSeg) * 256 + threadIdx.x) * 8;
    const float* src = (seg == 0) ? Qf : (seg == 1) ? Kf : Vf;

    float4 a = *(const float4*)(src + idx);
    float4 b = *(const float4*)(src + idx + 4);
    float fv[8] = {a.x, a.y, a.z, a.w, b.x, b.y, b.z, b.w};

    bf16x8 h8, l8;
    #pragma unroll
    for (int e = 0; e < 8; e++) {
        unsigned short hb = f2bf(fv[e]);
        h8[e] = (short)hb;
        l8[e] = (short)f2bf(fv[e] - bf2f(hb));
    }
    unsigned short* Hp = (seg == 0) ? Qh : (seg == 1) ? Kh : Vh;
    *(bf16x8*)(Hp + idx) = h8;
    if (seg < 2) {
        unsigned short* Lp = (seg == 0) ? Ql : Kl;
        *(bf16x8*)(Lp + idx) = l8;
    }
}

// ---------------------------------------------------------------------------
// Fused QKV projection, XCD-swizzled, 2-phase double-buffered (T3-minimum):
// STAGE(next tile -> buf^1) issued BEFORE compute(buf), ONE barrier per
// K-step (its implicit vmcnt(0) lands after compute covers the latency).
// A and B pre-split bf16.  Q outputs pre-scaled by 0.125 (exact pow2).
// LDS 64 KB (2 x 16K shorts).
// ---------------------------------------------------------------------------
__global__ __launch_bounds__(256)
void qkv_mfma(const unsigned short* __restrict__ Qsh, const unsigned short* __restrict__ Qsl,
              const unsigned short* __restrict__ Ksh, const unsigned short* __restrict__ Ksl,
              const unsigned short* __restrict__ Vsh,
              const unsigned short* __restrict__ Wqh, const unsigned short* __restrict__ Wql,
              const unsigned short* __restrict__ Wkh, const unsigned short* __restrict__ Wkl,
              const unsigned short* __restrict__ Wvh, const unsigned short* __restrict__ Wvl,
              const float* __restrict__ bq, const float* __restrict__ bk,
              const float* __restrict__ bv,
              unsigned short* __restrict__ qh, unsigned short* __restrict__ ql,
              unsigned short* __restrict__ kh, unsigned short* __restrict__ kl,
              unsigned short* __restrict__ vout)
{
    __shared__ short smem[32768];            // 2 buffers x 16384 shorts

    const int t    = threadIdx.x;
    const int lane = t & 63;
    const int w    = t >> 6;
    const int wm   = w >> 1;
    const int wn   = w & 1;

    int m_tile, nblk;
    swizzle_mn(blockIdx.x, 192, 6, m_tile, nblk);
    const int which = m_tile / 64;               // 0=Q 1=K 2=V
    const int m0    = (m_tile % 64) * 128;
    const int n0    = nblk * 128;

    const unsigned short* Ah = (which == 0) ? Qsh : (which == 1) ? Ksh : Vsh;
    const unsigned short* Al = (which == 0) ? Qsl : Ksl;   // unused for V
    const unsigned short* Bh = (which == 0) ? Wqh : (which == 1) ? Wkh : Wvh;
    const unsigned short* Bl = (which == 0) ? Wql : (which == 1) ? Wkl : Wvl;
    const float* bias = (which == 0) ? bq : (which == 1) ? bk : bv;

    f32x4 acc[4][4];
    #pragma unroll
    for (int i = 0; i < 4; i++)
        #pragma unroll
        for (int j = 0; j < 4; j++)
            acc[i][j] = (f32x4){0.f, 0.f, 0.f, 0.f};

    const int fr = lane & 15;
    const int q8 = (lane >> 4) * 8;

    auto stage = [&](int buf, int k0) {
        short* base = smem + buf * 16384;
        #pragma unroll
        for (int it = 0; it < 2; it++) {
            const int p   = t + 256 * it;
            const int row = p >> 2;
            const int c8  = (p & 3) * 8;
            GLDS(Ah + (size_t)(m0 + row) * Dsz + k0 + c8, base + p * 8);
            GLDS(Bh + (size_t)(n0 + row) * Dsz + k0 + c8, base + 8192 + p * 8);
            if (which < 2) {
                GLDS(Al + (size_t)(m0 + row) * Dsz + k0 + c8, base + 4096 + p * 8);
                GLDS(Bl + (size_t)(n0 + row) * Dsz + k0 + c8, base + 12288 + p * 8);
            }
        }
    };

    stage(0, 0);
    __syncthreads();
    int cur = 0;
    for (int k0 = 0; k0 < Dsz; k0 += 32) {
        if (k0 + 32 < Dsz) stage(cur ^ 1, k0 + 32);

        short* base = smem + cur * 16384;
        short* As_h = base;
        short* As_l = base + 4096;
        short* Bs_h = base + 8192;
        short* Bs_l = base + 12288;

        bf16x8 a_h[4], a_l[4], b_h[4], b_l[4];
        #pragma unroll
        for (int i = 0; i < 4; i++) {
            const int ra = (wm * 64 + i * 16 + fr) * 32 + q8;
            const int rb = (wn * 64 + i * 16 + fr) * 32 + q8;
            a_h[i] = *(const bf16x8*)&As_h[ra];
            b_h[i] = *(const bf16x8*)&Bs_h[rb];
            if (which < 2) {
                a_l[i] = *(const bf16x8*)&As_l[ra];
                b_l[i] = *(const bf16x8*)&Bs_l[rb];
            }
        }
        if (which < 2) {
            #pragma unroll
            for (int i = 0; i < 4; i++)
                #pragma unroll
                for (int j = 0; j < 4; j++) {
                    acc[i][j] = __builtin_amdgcn_mfma_f32_16x16x32_bf16(a_l[i], b_h[j], acc[i][j], 0, 0, 0);
                    acc[i][j] = __builtin_amdgcn_mfma_f32_16x16x32_bf16(a_h[i], b_l[j], acc[i][j], 0, 0, 0);
                    acc[i][j] = __builtin_amdgcn_mfma_f32_16x16x32_bf16(a_h[i], b_h[j], acc[i][j], 0, 0, 0);
                }
        } else {
            #pragma unroll
            for (int i = 0; i < 4; i++)
                #pragma unroll
                for (int j = 0; j < 4; j++)
                    acc[i][j] = __builtin_amdgcn_mfma_f32_16x16x32_bf16(a_h[i], b_h[j], acc[i][j], 0, 0, 0);
        }
        __syncthreads();                     // drains next-tile loads (vmcnt 0)
        cur ^= 1;
    }

    const int quad = lane >> 4;
    #pragma unroll
    for (int i = 0; i < 4; i++)
        #pragma unroll
        for (int j = 0; j < 4; j++) {
            const int n  = n0 + wn * 64 + j * 16 + fr;
            const float bn = bias[n];
            const int hh = n >> 6, dh = n & 63;
            #pragma unroll
            for (int r = 0; r < 4; r++) {
                const int m = m0 + wm * 64 + i * 16 + quad * 4 + r;
                const int bb = m >> 11, s = m & 2047;
                const size_t o = (((size_t)bb * Hn + hh) * Ssz + s) * DHn + dh;
                float v = acc[i][j][r] + bn;
                if (which == 0) {
                    v *= 0.125f;             // fold softmax scale (exact)
                    unsigned short hb = f2bf(v);
                    qh[o] = hb; ql[o] = f2bf(v - bf2f(hb));
                } else if (which == 1) {
                    unsigned short hb = f2bf(v);
                    kh[o] = hb; kl[o] = f2bf(v - bf2f(hb));
                } else {
                    vout[o] = f2bf(v);
                }
            }
        }
}

// ---------------------------------------------------------------------------
// Per-head transpose: [B,H,S,DH] bf16 -> [B,H,DH,S] bf16.
// ---------------------------------------------------------------------------
__global__ __launch_bounds__(256)
void vtrans_k(const unsigned short* __restrict__ src, unsigned short* __restrict__ dst)
{
    __shared__ unsigned short tl[32][33];
    const int s0 = blockIdx.x * 32;
    const int d0 = blockIdx.y * 32;
    const int hd = blockIdx.z;
    const int x = threadIdx.x, y = threadIdx.y;
    const size_t base = (size_t)hd * Ssz * DHn;
    #pragma unroll
    for (int i = 0; i < 4; i++)
        tl[y + 8 * i][x] = src[base + (size_t)(s0 + y + 8 * i) * DHn + d0 + x];
    __syncthreads();
    #pragma unroll
    for (int i = 0; i < 4; i++)
        dst[base + (size_t)(d0 + y + 8 * i) * Ssz + s0 + x] = tl[x][y + 8 * i];
}

// ---------------------------------------------------------------------------
// Generic MFMA GEMM, XCD-swizzled, 2-phase double-buffered (T3-minimum).
// A [M,K] bf16 (+opt lo); B [N,K] bf16 (+opt lo).  BM = 128 or 64.
// MODE 1: +bias +res, fp32 out.  MODE 2: GELU -> bf16 out.  MODE 3: fp32 out.
// ---------------------------------------------------------------------------
template<int MODE, bool ASPLIT, bool BSPLIT, int BM>
__global__ __launch_bounds__(256)
void gemm_mfma(const unsigned short* __restrict__ Ah, const unsigned short* __restrict__ Al,
               const unsigned short* __restrict__ Bh, const unsigned short* __restrict__ Bl,
               const float* __restrict__ bias, const float* __restrict__ res,
               float* __restrict__ Cf, unsigned short* __restrict__ Cb,
               int M, int N, int K)
{
    constexpr int MI = BM / 32;               // acc rows of 16 per wave
    constexpr int AE = BM * 32;               // A array elems (shorts)
    constexpr int NA = ASPLIT ? 2 : 1;
    constexpr int NB = BSPLIT ? 2 : 1;
    constexpr int BUFE = AE * NA + 4096 * NB; // one buffer, shorts
    __shared__ short smem[2 * BUFE];

    const int t    = threadIdx.x;
    const int lane = t & 63;
    const int w    = t >> 6;
    const int wm   = w >> 1;
    const int wn   = w & 1;

    int mt, nt_;
    swizzle_mn(blockIdx.x, M / BM, N >> 7, mt, nt_);
    const int m0 = mt * BM;
    const int n0 = nt_ * 128;

    f32x4 acc[MI][4];
    #pragma unroll
    for (int i = 0; i < MI; i++)
        #pragma unroll
        for (int j = 0; j < 4; j++)
            acc[i][j] = (f32x4){0.f, 0.f, 0.f, 0.f};

    const int fr = lane & 15;
    const int q8 = (lane >> 4) * 8;

    auto stage = [&](int buf, int k0) {
        short* base = smem + buf * BUFE;
        #pragma unroll
        for (int it = 0; it < BM / 64; it++) {
            const int p   = t + 256 * it;
            const int row = p >> 2;
            const int c8  = (p & 3) * 8;
            GLDS(Ah + (size_t)(m0 + row) * K + k0 + c8, base + p * 8);
            if (ASPLIT)
                GLDS(Al + (size_t)(m0 + row) * K + k0 + c8, base + AE + p * 8);
        }
        short* bbase = base + AE * NA;
        #pragma unroll
        for (int it = 0; it < 2; it++) {
            const int p   = t + 256 * it;
            const int row = p >> 2;
            const int c8  = (p & 3) * 8;
            GLDS(Bh + (size_t)(n0 + row) * K + k0 + c8, bbase + p * 8);
            if (BSPLIT)
                GLDS(Bl + (size_t)(n0 + row) * K + k0 + c8, bbase + 4096 + p * 8);
        }
    };

    stage(0, 0);
    __syncthreads();
    int cur = 0;
    for (int k0 = 0; k0 < K; k0 += 32) {
        if (k0 + 32 < K) stage(cur ^ 1, k0 + 32);

        short* base = smem + cur * BUFE;
        short* As_h = base;
        short* As_l = base + AE;
        short* Bs_h = base + AE * NA;
        short* Bs_l = Bs_h + 4096;

        bf16x8 a_h[MI], a_l[MI], b_h[4], b_l[4];
        #pragma unroll
        for (int i = 0; i < MI; i++) {
            const int ra = (wm * (BM / 2) + i * 16 + fr) * 32 + q8;
            a_h[i] = *(const bf16x8*)&As_h[ra];
            if (ASPLIT) a_l[i] = *(const bf16x8*)&As_l[ra];
        }
        #pragma unroll
        for (int j = 0; j < 4; j++) {
            const int rb = (wn * 64 + j * 16 + fr) * 32 + q8;
            b_h[j] = *(const bf16x8*)&Bs_h[rb];
            if (BSPLIT) b_l[j] = *(const bf16x8*)&Bs_l[rb];
        }
        #pragma unroll
        for (int i = 0; i < MI; i++)
            #pragma unroll
            for (int j = 0; j < 4; j++) {
                if (ASPLIT)
                    acc[i][j] = __builtin_amdgcn_mfma_f32_16x16x32_bf16(a_l[i], b_h[j], acc[i][j], 0, 0, 0);
                if (BSPLIT)
                    acc[i][j] = __builtin_amdgcn_mfma_f32_16x16x32_bf16(a_h[i], b_l[j], acc[i][j], 0, 0, 0);
                acc[i][j] = __builtin_amdgcn_mfma_f32_16x16x32_bf16(a_h[i], b_h[j], acc[i][j], 0, 0, 0);
            }
        __syncthreads();                     // drains next-tile loads
        cur ^= 1;
    }

    const int quad = lane >> 4;
    #pragma unroll
    for (int i = 0; i < MI; i++)
        #pragma unroll
        for (int j = 0; j < 4; j++) {
            const int n  = n0 + wn * 64 + j * 16 + fr;
            const float bn = bias[n];
            #pragma unroll
            for (int r = 0; r < 4; r++) {
                const int m = m0 + wm * (BM / 2) + i * 16 + quad * 4 + r;
                float v = acc[i][j][r] + bn;
                if (MODE == 1) {
                    v += res[(size_t)m * N + n];
                    Cf[(size_t)m * N + n] = v;
                } else if (MODE == 2) {
                    v = 0.5f * v * (1.0f + erff(v * 0.70710678118654752f));
                    Cb[(size_t)m * N + n] = f2bf(v);
                } else {
                    Cf[(size_t)m * N + n] = v;
                }
            }
        }
}

// ---------------------------------------------------------------------------
// MFMA flash attention (R3 structure, 143 us measured): shift-free softmax,
// Q pre-scaled by 1/8, 4 waves x 16 q-rows, QBLK=64, KVBLK=64, setprio.
// ---------------------------------------------------------------------------
__device__ __forceinline__ void stage16(const unsigned short* src, short* dst,
                                        int p0, int lane, int row0, int rstride, int col0)
{
    const int p   = p0 + lane;
    const int n   = p >> 3;
    const int cst = (p & 7) ^ (n & 7);
    const unsigned short* g = src + (size_t)(row0 + n) * rstride + col0 + cst * 8;
    GLDS(g, dst + p0 * 8);
}

__device__ __forceinline__ bf16x8 frag(const short* arr, int row, int c)
{
    const int pos = row * 8 + (c ^ (row & 7));
    return *(const bf16x8*)&arr[pos * 8];
}

__global__ __launch_bounds__(256)
void attn_mfma(const unsigned short* __restrict__ qh, const unsigned short* __restrict__ ql,
               const unsigned short* __restrict__ kh, const unsigned short* __restrict__ kl,
               const unsigned short* __restrict__ vt, unsigned short* __restrict__ ch)
{
    const int hid = blockIdx.x;
    const int b   = hid / Hn;
    const int h   = hid - b * Hn;
    const int q0  = blockIdx.y * 64;
    const int t    = threadIdx.x;
    const int lane = t & 63;
    const int w    = t >> 6;
    const int fr   = lane & 15;
    const int quad = lane >> 4;

    __shared__ short sKV[12288];             // Kh, Kl, Vh : 24 KB
    __shared__ short sQP[8192];              // Qh+Ql 16 KB -> P fp32 after kt 0
    short* Kh_s = sKV;
    short* Kl_s = sKV + 4096;
    short* Vh_s = sKV + 8192;
    short* Qh_s = sQP;
    short* Ql_s = sQP + 4096;
    float* Pw   = (float*)sQP + w * 1024;

    const size_t hoff = (size_t)hid * Ssz * DHn;

    stage16(qh + hoff, Qh_s, w * 128,      lane, q0, DHn, 0);
    stage16(qh + hoff, Qh_s, w * 128 + 64, lane, q0, DHn, 0);
    stage16(ql + hoff, Ql_s, w * 128,      lane, q0, DHn, 0);
    stage16(ql + hoff, Ql_s, w * 128 + 64, lane, q0, DHn, 0);

    f32x4 O[4];
    #pragma unroll
    for (int d = 0; d < 4; d++) O[d] = (f32x4){0.f, 0.f, 0.f, 0.f};
    float lp[4] = {0.f, 0.f, 0.f, 0.f};

    bf16x8 qfh[2], qfl[2];

    for (int kt = 0; kt < Ssz / 64; kt++) {
        __syncthreads();
        const int kr = kt * 64;
        #pragma unroll
        for (int bt = 0; bt < 2; bt++) {
            const int p0 = w * 128 + bt * 64;
            stage16(kh + hoff, Kh_s, p0, lane, kr, DHn, 0);
            stage16(kl + hoff, Kl_s, p0, lane, kr, DHn, 0);
            stage16(vt + hoff, Vh_s, p0, lane, 0, Ssz, kr);
        }
        __syncthreads();

        if (kt == 0) {
            #pragma unroll
            for (int kc = 0; kc < 2; kc++) {
                qfh[kc] = frag(Qh_s, w * 16 + fr, kc * 4 + quad);
                qfl[kc] = frag(Ql_s, w * 16 + fr, kc * 4 + quad);
            }
            __syncthreads();                 // Q in regs; sQP becomes P space
        }

        f32x4 sc[4];
        #pragma unroll
        for (int nt = 0; nt < 4; nt++) sc[nt] = (f32x4){0.f, 0.f, 0.f, 0.f};
        __builtin_amdgcn_s_setprio(1);
        #pragma unroll
        for (int nt = 0; nt < 4; nt++)
            #pragma unroll
            for (int kc = 0; kc < 2; kc++) {
                bf16x8 bh = frag(Kh_s, nt * 16 + fr, kc * 4 + quad);
                bf16x8 bl = frag(Kl_s, nt * 16 + fr, kc * 4 + quad);
                sc[nt] = __builtin_amdgcn_mfma_f32_16x16x32_bf16(qfl[kc], bh, sc[nt], 0, 0, 0);
                sc[nt] = __builtin_amdgcn_mfma_f32_16x16x32_bf16(qfh[kc], bl, sc[nt], 0, 0, 0);
                sc[nt] = __builtin_amdgcn_mfma_f32_16x16x32_bf16(qfh[kc], bh, sc[nt], 0, 0, 0);
            }
        __builtin_amdgcn_s_setprio(0);

        #pragma unroll
        for (int r = 0; r < 4; r++) {
            const int m = quad * 4 + r;
            #pragma unroll
            for (int nt = 0; nt < 4; nt++) {
                float p = __expf(sc[nt][r]);          // scale pre-folded into Q
                const int j  = nt * 16 + fr;
                const int c4 = j >> 2;
                Pw[(m * 16 + (c4 ^ m)) * 4 + (j & 3)] = p;
                lp[r] += p;
            }
        }

        #pragma unroll
        for (int kc = 0; kc < 2; kc++) {
            const int c4a = kc * 8 + quad * 2;
            float4 pa = *(float4*)&Pw[(fr * 16 + (c4a ^ fr)) * 4];
            float4 pb = *(float4*)&Pw[(fr * 16 + ((c4a + 1) ^ fr)) * 4];
            union { bf16x8 v; __hip_bfloat162 b2[4]; } P;
            P.b2[0] = __float22bfloat162_rn(make_float2(pa.x, pa.y));
            P.b2[1] = __float22bfloat162_rn(make_float2(pa.z, pa.w));
            P.b2[2] = __float22bfloat162_rn(make_float2(pb.x, pb.y));
            P.b2[3] = __float22bfloat162_rn(make_float2(pb.z, pb.w));
            __builtin_amdgcn_s_setprio(1);
            #pragma unroll
            for (int dt = 0; dt < 4; dt++) {
                bf16x8 vh = frag(Vh_s, dt * 16 + fr, kc * 4 + quad);
                O[dt] = __builtin_amdgcn_mfma_f32_16x16x32_bf16(P.v, vh, O[dt], 0, 0, 0);
            }
            __builtin_amdgcn_s_setprio(0);
        }
    }

    #pragma unroll
    for (int r = 0; r < 4; r++) {
        float ls = lp[r];
        #pragma unroll
        for (int msk = 1; msk < 16; msk <<= 1) ls += __shfl_xor(ls, msk);
        const float linv = 1.0f / ls;
        const int s = q0 + w * 16 + quad * 4 + r;
        unsigned short* och = ch + ((size_t)b * Ssz + s) * Dsz + h * DHn;
        #pragma unroll
        for (int dt = 0; dt < 4; dt++)
            och[dt * 16 + fr] = f2bf(O[dt][r] * linv);
    }
}

// ---------------------------------------------------------------------------
// LayerNorm over D=768; writes single bf16 (FFN1 is 2-term: A-hi only).
// ---------------------------------------------------------------------------
__global__ __launch_bounds__(256)
void ln_k(const float* __restrict__ x, const float* __restrict__ g,
          const float* __restrict__ bb, unsigned short* __restrict__ yh)
{
    const int row = blockIdx.x;
    const float* xr = x + (size_t)row * Dsz;
    unsigned short* yhr = yh + (size_t)row * Dsz;
    const int t = threadIdx.x;

    float v0 = xr[t], v1 = xr[t + 256], v2 = xr[t + 512];
    float s = v0 + v1 + v2;
    #pragma unroll
    for (int o = 1; o < 64; o <<= 1) s += __shfl_xor(s, o, 64);

    __shared__ float red1[4];
    __shared__ float red2[4];
    const int wid = t >> 6, lane = t & 63;
    if (lane == 0) red1[wid] = s;
    __syncthreads();
    const float mean = (red1[0] + red1[1] + red1[2] + red1[3]) * (1.0f / Dsz);

    float d0 = v0 - mean, d1 = v1 - mean, d2 = v2 - mean;
    float vs = d0 * d0 + d1 * d1 + d2 * d2;
    #pragma unroll
    for (int o = 1; o < 64; o <<= 1) vs += __shfl_xor(vs, o, 64);
    if (lane == 0) red2[wid] = vs;
    __syncthreads();
    const float var = (red2[0] + red2[1] + red2[2] + red2[3]) * (1.0f / Dsz);
    const float inv = rsqrtf(var + EPSL);

    yhr[t]       = f2bf(d0 * inv * g[t]       + bb[t]);
    yhr[t + 256] = f2bf(d1 * inv * g[t + 256] + bb[t + 256]);
    yhr[t + 512] = f2bf(d2 * inv * g[t + 512] + bb[t + 512]);
}

// ---------------------------------------------------------------------------
extern "C" void kernel_launch(void* const* d_in, const int* in_sizes, int n_in,
                              void* d_out, int out_size, void* d_ws, size_t ws_size,
                              hipStream_t stream)
{
    (void)in_sizes; (void)n_in; (void)out_size; (void)ws_size;
    const float* Q    = (const float*)d_in[0];
    const float* Kin  = (const float*)d_in[1];
    const float* Vin  = (const float*)d_in[2];
    const float* Wq   = (const float*)d_in[3];
    const float* bq   = (const float*)d_in[4];
    const float* Wk   = (const float*)d_in[5];
    const float* bk   = (const float*)d_in[6];
    const float* Wv   = (const float*)d_in[7];
    const float* bv   = (const float*)d_in[8];
    const float* Wo   = (const float*)d_in[9];
    const float* bo   = (const float*)d_in[10];
    const float* ln_g = (const float*)d_in[11];
    const float* ln_b = (const float*)d_in[12];
    const float* W1   = (const float*)d_in[13];
    const float* b1   = (const float*)d_in[14];
    const float* W2   = (const float*)d_in[15];
    const float* b2   = (const float*)d_in[16];
    float* out = (float*)d_out;

    const size_t NT = (size_t)NTOK * Dsz;              // 6291456 elems
    unsigned short* usws = (unsigned short*)d_ws;
    unsigned short* qh  = usws + 0 * NT;
    unsigned short* ql  = usws + 1 * NT;
    unsigned short* kh  = usws + 2 * NT;               // later LN-out hh
    unsigned short* kl  = usws + 3 * NT;
    unsigned short* vt  = usws + 4 * NT;
    unsigned short* ch  = usws + 6 * NT;               // V pre-T; later ctx bf16
    unsigned short* wsp = usws + 8 * NT;
    const size_t SW = (size_t)Dsz * Dsz;
    unsigned short* Wqh = wsp + 0 * SW;
    unsigned short* Wql = wsp + 1 * SW;
    unsigned short* Wkh = wsp + 2 * SW;
    unsigned short* Wkl = wsp + 3 * SW;
    unsigned short* Wvh = wsp + 4 * SW;
    unsigned short* Wvl = wsp + 5 * SW;
    unsigned short* Woh = wsp + 6 * SW;
    unsigned short* Wol = wsp + 7 * SW;
    unsigned short* W1h = wsp + 8 * SW;
    unsigned short* W1l = wsp + 12 * SW;
    unsigned short* W2h = wsp + 16 * SW;
    unsigned short* W2l = wsp + 20 * SW;
    float*          hpre = (float*)usws;               // fp32 over qh+ql
    unsigned short* hh   = kh;
    unsigned short* hbuf = usws + 4 * NT;              // FFN hidden bf16 [8192,3072]

    // presplit scratch: regions free until vtrans/FFN2.
    unsigned short* Qsh = usws + 4 * NT;
    unsigned short* Qsl = usws + 5 * NT;
    unsigned short* Ksh = usws + 7 * NT;
    unsigned short* Ksl = (unsigned short*)d_out;
    unsigned short* Vsh = (unsigned short*)d_out + NT;

    dim3 wb(32, 8);
    wsplit_k<<<dim3(Dsz / 32, Dsz / 32), wb, 0, stream>>>(Wq, Wqh, Wql, Dsz, Dsz);
    wsplit_k<<<dim3(Dsz / 32, Dsz / 32), wb, 0, stream>>>(Wk, Wkh, Wkl, Dsz, Dsz);
    wsplit_k<<<dim3(Dsz / 32, Dsz / 32), wb, 0, stream>>>(Wv, Wvh, Wvl, Dsz, Dsz);
    wsplit_k<<<dim3(Dsz / 32, Dsz / 32), wb, 0, stream>>>(Wo, Woh, Wol, Dsz, Dsz);
    wsplit_k<<<dim3(DFn / 32, Dsz / 32), wb, 0, stream>>>(W1, W1h, W1l, Dsz, DFn);
    wsplit_k<<<dim3(Dsz / 32, DFn / 32), wb, 0, stream>>>(W2, W2h, W2l, DFn, Dsz);

    // input presplit: Q,K -> hi+lo; V -> hi.
    presplit_k<<<3 * (NTOK * Dsz / 2048), 256, 0, stream>>>(
        Q, Kin, Vin, Qsh, Qsl, Ksh, Ksl, Vsh);

    // fused QKV projections, swizzled, 2-phase dbuf (V -> single bf16 into ch)
    qkv_mfma<<<1152, 256, 0, stream>>>(
        Qsh, Qsl, Ksh, Ksl, Vsh,
        Wqh, Wql, Wkh, Wkl, Wvh, Wvl, bq, bk, bv,
        qh, ql, kh, kl, ch);

    // V transpose -> vt [B,H,DH,S]
    vtrans_k<<<dim3(Ssz / 32, DHn / 32, Bsz * Hn), wb, 0, stream>>>(ch, vt);

    // flash attention -> ctx bf16 (ch); R3 structure
    attn_mfma<<<dim3(Bsz * Hn, Ssz / 64), 256, 0, stream>>>(qh, ql, kh, kl, vt, ch);

    // O projection (2-term) + bias + residual(Q) -> hpre fp32.  BM=64.
    gemm_mfma<1, false, true, 64><<<768, 256, 0, stream>>>(
        ch, nullptr, Woh, Wol, bo, Q, hpre, nullptr, NTOK, Dsz, Dsz);

    // LayerNorm -> single bf16 over kh
    ln_k<<<NTOK, 256, 0, stream>>>(hpre, ln_g, ln_b, hh);

    // FFN: FFN1 2-term (GELU -> bf16 hidden) BM=128 grid 1536;
    //      FFN2 1-term (fp32 out) BM=64 grid 768.
    gemm_mfma<2, false, true, 128><<<1536, 256, 0, stream>>>(
        hh, nullptr, W1h, W1l, b1, nullptr, nullptr, hbuf, NTOK, DFn, Dsz);
    gemm_mfma<3, false, false, 64><<<768, 256, 0, stream>>>(
        hbuf, nullptr, W2h, nullptr, b2, nullptr, out, nullptr, NTOK, Dsz, DFn);
}